// Round 8
// baseline (15548.105 us; speedup 1.0000x reference)
//
#include <hip/hip_runtime.h>

#define H 1024
#define V 32000
#define STEPS 375
#define NB1 256     // gru blocks
#define NB2 512     // logits blocks (2 per CU)
#define DELTA 0.25f // bf16->fp32 rescue margin (>=10x worst-case bf16 dot error)

__device__ __forceinline__ float dot4(const float4 a, const float4 b) {
    return fmaf(a.x, b.x, fmaf(a.y, b.y, fmaf(a.z, b.z, a.w * b.w)));
}

__device__ __forceinline__ float wave_sum(float v) {
#pragma unroll
    for (int off = 32; off > 0; off >>= 1) v += __shfl_xor(v, off);
    return v;
}

__device__ __forceinline__ void sm_merge(float& m, float& ss, int& a,
                                         float om, float os, int oa) {
    if (om > m || (om == m && oa < a)) {
        ss = os + ss * expf(m - om); m = om; a = oa;
    } else {
        ss += os * expf(om - m);
    }
}

__device__ __forceinline__ float bl(unsigned u) { return __uint_as_float(u << 16); }
__device__ __forceinline__ float bh(unsigned u) { return __uint_as_float(u & 0xffff0000u); }

__device__ __forceinline__ unsigned f2bf(float f) {   // RNE fp32->bf16
    unsigned u = __float_as_uint(f);
    return (u + 0x7fffu + ((u >> 16) & 1u)) >> 16;
}

// ---------------- init: h0 = enc ----------------
__global__ void init_kernel(const float* __restrict__ enc, float* __restrict__ h0) {
    for (int i = threadIdx.x; i < H; i += 256) h0[i] = enc[i];
}

// ---------------- one-time: lin_W fp32 -> packed bf16 ----------------
__global__ __launch_bounds__(512) void conv_kernel(const float* __restrict__ src,
                                                   unsigned short* __restrict__ dst) {
    const size_t idx = (size_t)blockIdx.x * 512 + threadIdx.x;  // 4,096,000 total
    const float4* s4 = (const float4*)src;
    float4 a = s4[2 * idx], b = s4[2 * idx + 1];
    uint4 o;
    o.x = f2bf(a.x) | (f2bf(a.y) << 16);
    o.y = f2bf(a.z) | (f2bf(a.w) << 16);
    o.z = f2bf(b.x) | (f2bf(b.y) << 16);
    o.w = f2bf(b.z) | (f2bf(b.w) << 16);
    ((uint4*)dst)[idx] = o;
}

// ---------------- per-step GRU (argmax feedback; logz[s-1] out) ----------------
__global__ __launch_bounds__(256) void gru_kernel(
    const float* __restrict__ emb, const float* __restrict__ W_ih,
    const float* __restrict__ W_hh, const float* __restrict__ b_ih,
    const float* __restrict__ b_hh, const float* __restrict__ h_cur,
    float* __restrict__ h_next, float* __restrict__ logz,
    const float* __restrict__ pm, const float* __restrict__ ps,
    const int* __restrict__ pa, int s) {
    const int tid = threadIdx.x;
    const int lane = tid & 63;
    const int wv = tid >> 6;
    const int b = blockIdx.x;
    const int i = b * 4 + wv;   // GRU output row (4 waves, one row each)

    // issue weight + h loads first; their latency overlaps the argmax reduce
    const float4* hp = (const float4*)h_cur;
    float4 hv[4];
    float4 WX0[4], WX1[4], WX2[4], WH0[4], WH1[4], WH2[4];
#pragma unroll
    for (int j = 0; j < 4; ++j) {
        const int idx = lane + 64 * j;
        hv[j] = hp[idx];
        WX0[j] = ((const float4*)(W_ih + (size_t)i * H))[idx];
        WX1[j] = ((const float4*)(W_ih + ((size_t)i + H) * H))[idx];
        WX2[j] = ((const float4*)(W_ih + ((size_t)i + 2 * H) * H))[idx];
        WH0[j] = ((const float4*)(W_hh + (size_t)i * H))[idx];
        WH1[j] = ((const float4*)(W_hh + ((size_t)i + H) * H))[idx];
        WH2[j] = ((const float4*)(W_hh + ((size_t)i + 2 * H) * H))[idx];
    }

    int tok = 0;
    if (s > 0) {
        float m = -3.4e38f, ss = 0.f;
        int a = 0x7fffffff;
#pragma unroll
        for (int k = 0; k < NB2 / 64; ++k)
            sm_merge(m, ss, a, pm[k * 64 + lane], ps[k * 64 + lane], pa[k * 64 + lane]);
#pragma unroll
        for (int off = 32; off > 0; off >>= 1) {
            float om = __shfl_xor(m, off), os = __shfl_xor(ss, off);
            int oa = __shfl_xor(a, off);
            sm_merge(m, ss, a, om, os, oa);
        }
        tok = a;
        if (b == 0 && tid == 0) logz[s - 1] = m + logf(ss);
    }

    const float4* xp = (const float4*)(emb + (size_t)tok * H);
    float4 xv[4];
#pragma unroll
    for (int j = 0; j < 4; ++j) xv[j] = xp[lane + 64 * j];

    float sx0 = 0, sx1 = 0, sx2 = 0, sh0 = 0, sh1 = 0, sh2 = 0;
#pragma unroll
    for (int j = 0; j < 4; ++j) {
        sx0 += dot4(WX0[j], xv[j]); sx1 += dot4(WX1[j], xv[j]); sx2 += dot4(WX2[j], xv[j]);
        sh0 += dot4(WH0[j], hv[j]); sh1 += dot4(WH1[j], hv[j]); sh2 += dot4(WH2[j], hv[j]);
    }
    sx0 = wave_sum(sx0); sx1 = wave_sum(sx1); sx2 = wave_sum(sx2);
    sh0 = wave_sum(sh0); sh1 = wave_sum(sh1); sh2 = wave_sum(sh2);
    if (lane == 0) {
        const float rg = 1.f / (1.f + expf(-((sx0 + b_ih[i]) + (sh0 + b_hh[i]))));
        const float zg = 1.f / (1.f + expf(-((sx1 + b_ih[i + H]) + (sh1 + b_hh[i + H]))));
        const float ng = tanhf((sx2 + b_ih[i + 2 * H]) + rg * (sh2 + b_hh[i + 2 * H]));
        h_next[i] = (1.f - zg) * ng + zg * h_cur[i];
    }
}

// ---------------- per-step logits: bf16 GEMV + fp32 rescue of near-max rows ----
__global__ __launch_bounds__(512, 4) void logits_bf16_kernel(
    const unsigned short* __restrict__ wbf, const float* __restrict__ lin_W,
    const float* __restrict__ lin_b, const float* __restrict__ h_src,
    float* __restrict__ orow, float* __restrict__ pm, float* __restrict__ ps,
    int* __restrict__ pa) {
    const int tid = threadIdx.x;
    const int lane = tid & 63;
    const int wv = tid >> 6;
    const int b = blockIdx.x;
    const int row0 = (b < 256) ? 63 * b : 16128 + 62 * (b - 256);
    const int nrows = (b < 256) ? 63 : 62;

    __shared__ float red_m[8], red_s[8];
    __shared__ float s_cm[8];
    __shared__ int s_ca[8];

    // h fragments in bf16-row layout: lane covers elems [8l..8l+7] and [512+8l..+7]
    const float4* h4 = (const float4*)h_src;
    const float4 ha0 = h4[2 * lane], ha1 = h4[2 * lane + 1];
    const float4 hb0 = h4[128 + 2 * lane], hb1 = h4[129 + 2 * lane];
    const float h0[8] = {ha0.x, ha0.y, ha0.z, ha0.w, ha1.x, ha1.y, ha1.z, ha1.w};
    const float h1[8] = {hb0.x, hb0.y, hb0.z, hb0.w, hb1.x, hb1.y, hb1.z, hb1.w};

    float lg[8];               // per-slot logit (wave-uniform after wave_sum)
    float m = -3.4e38f, ssum = 0.f;

#pragma unroll
    for (int half = 0; half < 2; ++half) {
        const int k0 = half * 4;
        uint4 qa[4], qb[4];
        int rr[4];
        bool val[4];
#pragma unroll
        for (int i2 = 0; i2 < 4; ++i2) {
            rr[i2] = wv + 8 * (k0 + i2);
            val[i2] = rr[i2] < nrows;
            const uint4* wp = (const uint4*)(wbf + (size_t)(row0 + (val[i2] ? rr[i2] : 0)) * H);
            qa[i2] = wp[lane];
            qb[i2] = wp[64 + lane];
        }
        __builtin_amdgcn_sched_barrier(0);
#pragma unroll
        for (int i2 = 0; i2 < 4; ++i2) {
            float a = 0.f;
            a = fmaf(bl(qa[i2].x), h0[0], a); a = fmaf(bh(qa[i2].x), h0[1], a);
            a = fmaf(bl(qa[i2].y), h0[2], a); a = fmaf(bh(qa[i2].y), h0[3], a);
            a = fmaf(bl(qa[i2].z), h0[4], a); a = fmaf(bh(qa[i2].z), h0[5], a);
            a = fmaf(bl(qa[i2].w), h0[6], a); a = fmaf(bh(qa[i2].w), h0[7], a);
            a = fmaf(bl(qb[i2].x), h1[0], a); a = fmaf(bh(qb[i2].x), h1[1], a);
            a = fmaf(bl(qb[i2].y), h1[2], a); a = fmaf(bh(qb[i2].y), h1[3], a);
            a = fmaf(bl(qb[i2].z), h1[4], a); a = fmaf(bh(qb[i2].z), h1[5], a);
            a = fmaf(bl(qb[i2].w), h1[6], a); a = fmaf(bh(qb[i2].w), h1[7], a);
            a = wave_sum(a);
            if (val[i2]) {
                const int col = row0 + rr[i2];
                a += lin_b[col];
                lg[k0 + i2] = a;
                if (lane == 0) __builtin_nontemporal_store(a, &orow[col]);
                if (a > m) { ssum *= expf(m - a); m = a; }
                ssum += expf(a - m);
            } else {
                lg[k0 + i2] = -3.4e38f;
            }
        }
    }
    if (lane == 0) { red_m[wv] = m; red_s[wv] = ssum; }
    __syncthreads();

    // block bf16 max (every thread computes from shared)
    float Mb = red_m[0];
#pragma unroll
    for (int w = 1; w < 8; ++w) Mb = fmaxf(Mb, red_m[w]);

    // fp32 rescue of candidate rows (wave-uniform predicate; ~0-1 per wave)
    float cm = -3.4e38f;
    int ca = 0x7fffffff;
    float4 hv[4];
    bool loaded = false;
#pragma unroll
    for (int k = 0; k < 8; ++k) {
        if (lg[k] > Mb - DELTA) {
            const int row = row0 + wv + 8 * k;
            if (!loaded) {
#pragma unroll
                for (int j = 0; j < 4; ++j) hv[j] = h4[lane + 64 * j];
                loaded = true;
            }
            const float4* rp = (const float4*)(lin_W + (size_t)row * H);
            float a = 0.f;
#pragma unroll
            for (int j = 0; j < 4; ++j) a += dot4(rp[lane + 64 * j], hv[j]);
            a = wave_sum(a) + lin_b[row];
            if (a > cm || (a == cm && row < ca)) { cm = a; ca = row; }
        }
    }
    if (lane == 0) { s_cm[wv] = cm; s_ca[wv] = ca; }
    __syncthreads();
    if (tid == 0) {
        float M = red_m[0], S = red_s[0];
#pragma unroll
        for (int w = 1; w < 8; ++w) {   // merge sums (no argmax component)
            const float mw = red_m[w], sw = red_s[w];
            if (mw > M) { S = sw + S * expf(M - mw); M = mw; }
            else S += sw * expf(mw - M);
        }
        float CM = s_cm[0];
        int CA = s_ca[0];
#pragma unroll
        for (int w = 1; w < 8; ++w)
            if (s_cm[w] > CM || (s_cm[w] == CM && s_ca[w] < CA)) { CM = s_cm[w]; CA = s_ca[w]; }
        pm[b] = CM;                    // fp32-exact block max (argmax-safe)
        ps[b] = S * expf(M - CM);      // bf16 sumexp re-anchored to CM
        pa[b] = CA;
    }
}

// ---------------- fallback fp32 logits (if ws too small for bf16 copy) --------
__global__ __launch_bounds__(512, 4) void logits_fp32_kernel(
    const float* __restrict__ lin_W, const float* __restrict__ lin_b,
    const float* __restrict__ h_src, float* __restrict__ orow,
    float* __restrict__ pm, float* __restrict__ ps, int* __restrict__ pa) {
    const int tid = threadIdx.x;
    const int lane = tid & 63;
    const int wv = tid >> 6;
    const int b = blockIdx.x;
    const int row0 = (b < 256) ? 63 * b : 16128 + 62 * (b - 256);
    const int nrows = (b < 256) ? 63 : 62;

    __shared__ float red_m[8], red_s[8];
    __shared__ int red_a[8];

    const float4* h4 = (const float4*)h_src;
    float4 hr[4];
#pragma unroll
    for (int j = 0; j < 4; ++j) hr[j] = h4[lane + 64 * j];

    float m = -3.4e38f, ssum = 0.f;
    int arg = 0x7fffffff;
    for (int r = wv; r < nrows; r += 32) {
        const int rB = r + 8, rC = r + 16, rD = r + 24;
        const bool vB = rB < nrows, vC = rC < nrows, vD = rD < nrows;
        float4 wA[4], wB[4], wC[4], wD[4];
#pragma unroll
        for (int j = 0; j < 4; ++j) {
            const int idx = lane + 64 * j;
            wA[j] = ((const float4*)(lin_W + (size_t)(row0 + r) * H))[idx];
            wB[j] = ((const float4*)(lin_W + (size_t)(row0 + (vB ? rB : r)) * H))[idx];
            wC[j] = ((const float4*)(lin_W + (size_t)(row0 + (vC ? rC : r)) * H))[idx];
            wD[j] = ((const float4*)(lin_W + (size_t)(row0 + (vD ? rD : r)) * H))[idx];
        }
        __builtin_amdgcn_sched_barrier(0);
        float aA = 0, aB = 0, aC = 0, aD = 0;
#pragma unroll
        for (int j = 0; j < 4; ++j) {
            aA += dot4(wA[j], hr[j]); aB += dot4(wB[j], hr[j]);
            aC += dot4(wC[j], hr[j]); aD += dot4(wD[j], hr[j]);
        }
        aA = wave_sum(aA); aB = wave_sum(aB);
        aC = wave_sum(aC); aD = wave_sum(aD);
        aA += lin_b[row0 + r];
        if (lane == 0) __builtin_nontemporal_store(aA, &orow[row0 + r]);
        if (aA > m) { ssum *= expf(m - aA); m = aA; arg = row0 + r; }
        ssum += expf(aA - m);
        if (vB) {
            aB += lin_b[row0 + rB];
            if (lane == 0) __builtin_nontemporal_store(aB, &orow[row0 + rB]);
            if (aB > m) { ssum *= expf(m - aB); m = aB; arg = row0 + rB; }
            ssum += expf(aB - m);
        }
        if (vC) {
            aC += lin_b[row0 + rC];
            if (lane == 0) __builtin_nontemporal_store(aC, &orow[row0 + rC]);
            if (aC > m) { ssum *= expf(m - aC); m = aC; arg = row0 + rC; }
            ssum += expf(aC - m);
        }
        if (vD) {
            aD += lin_b[row0 + rD];
            if (lane == 0) __builtin_nontemporal_store(aD, &orow[row0 + rD]);
            if (aD > m) { ssum *= expf(m - aD); m = aD; arg = row0 + rD; }
            ssum += expf(aD - m);
        }
    }
    if (lane == 0) { red_m[wv] = m; red_s[wv] = ssum; red_a[wv] = arg; }
    __syncthreads();
    if (tid == 0) {
        float M = red_m[0], S = red_s[0];
        int A = red_a[0];
#pragma unroll
        for (int w = 1; w < 8; ++w) sm_merge(M, S, A, red_m[w], red_s[w], red_a[w]);
        pm[b] = M; ps[b] = S; pa[b] = A;
    }
}

// ---------------- final: out[s] -= logz[s] for s in 0..STEPS-2 ----------------
__global__ __launch_bounds__(256) void final_kernel(float* __restrict__ out,
                                                    const float* __restrict__ logz) {
    const int row = blockIdx.x >> 3;
    const int seg = blockIdx.x & 7;
    const float lz = logz[row];
    float4* p = (float4*)(out + (size_t)row * V) + seg * 1000;
    for (int i = threadIdx.x; i < 1000; i += 256) {
        float4 v = p[i];
        v.x -= lz; v.y -= lz; v.z -= lz; v.w -= lz;
        p[i] = v;
    }
}

// ---------------- tail: finalize out[STEPS-1] + write h_final ----------------
__global__ __launch_bounds__(256) void tail_kernel(
    float* __restrict__ out_last, const float* __restrict__ pm,
    const float* __restrict__ ps, const int* __restrict__ pa,
    const float* __restrict__ h_final, float* __restrict__ out_h) {
    const int tid = threadIdx.x;
    const int lane = tid & 63;
    const int b = blockIdx.x;
    float m = -3.4e38f, ss = 0.f;
    int a = 0x7fffffff;
#pragma unroll
    for (int k = 0; k < NB2 / 64; ++k)
        sm_merge(m, ss, a, pm[k * 64 + lane], ps[k * 64 + lane], pa[k * 64 + lane]);
#pragma unroll
    for (int off = 32; off > 0; off >>= 1) {
        float om = __shfl_xor(m, off), os = __shfl_xor(ss, off);
        int oa = __shfl_xor(a, off);
        sm_merge(m, ss, a, om, os, oa);
    }
    const float logZ = m + logf(ss);
    if (tid < 125) out_last[b * 125 + tid] -= logZ;
    if (b == 0)
        for (int i = tid; i < H; i += 256) out_h[i] = h_final[i];
}

extern "C" void kernel_launch(void* const* d_in, const int* in_sizes, int n_in,
                              void* d_out, int out_size, void* d_ws, size_t ws_size,
                              hipStream_t stream) {
    const float* enc = (const float*)d_in[0];
    const float* emb = (const float*)d_in[1];
    const float* W_ih = (const float*)d_in[2];
    const float* W_hh = (const float*)d_in[3];
    const float* b_ih = (const float*)d_in[4];
    const float* b_hh = (const float*)d_in[5];
    const float* lin_W = (const float*)d_in[6];
    const float* lin_b = (const float*)d_in[7];
    float* out = (float*)d_out;
    float* ws = (float*)d_ws;

    // ws: h_buf[2][H] | pm[NB2] | ps[NB2] | pa[NB2](int) | logz[STEPS] | pad | wbf
    float* h_buf = ws;
    float* pm = ws + 2 * H;
    float* ps = pm + NB2;
    int* pa = (int*)(ps + NB2);
    float* logz = (float*)(pa + NB2);
    unsigned short* wbf = (unsigned short*)((char*)d_ws + 16384);
    const size_t need = 16384 + (size_t)V * H * 2;
    const bool bf16path = ws_size >= need;

    init_kernel<<<1, 256, 0, stream>>>(enc, h_buf);
    if (bf16path)
        conv_kernel<<<V * H / 8 / 512, 512, 0, stream>>>(lin_W, wbf);
    for (int s = 0; s < STEPS; ++s) {
        float* h_cur = h_buf + (s & 1) * H;
        float* h_next = h_buf + ((s + 1) & 1) * H;
        gru_kernel<<<NB1, 256, 0, stream>>>(emb, W_ih, W_hh, b_ih, b_hh,
                                            h_cur, h_next, logz, pm, ps, pa, s);
        if (bf16path)
            logits_bf16_kernel<<<NB2, 512, 0, stream>>>(wbf, lin_W, lin_b, h_next,
                                                        out + (size_t)s * V, pm, ps, pa);
        else
            logits_fp32_kernel<<<NB2, 512, 0, stream>>>(lin_W, lin_b, h_next,
                                                        out + (size_t)s * V, pm, ps, pa);
    }
    final_kernel<<<(STEPS - 1) * 8, 256, 0, stream>>>(out, logz);
    tail_kernel<<<NB1, 256, 0, stream>>>(out + (size_t)(STEPS - 1) * V, pm, ps, pa,
                                         h_buf + (STEPS & 1) * H,
                                         out + (size_t)V * STEPS);
}

// Round 9
// 15426.582 us; speedup vs baseline: 1.0079x; 1.0079x over previous
//
#include <hip/hip_runtime.h>

#define H 1024
#define V 32000
#define STEPS 375
#define NB1 256     // gru blocks
#define NB2 512     // logits blocks (2 per CU)
#define DELTA 0.0625f // bf16->fp32 rescue margin (~15x the 5.7-sigma bf16 dot error)

__device__ __forceinline__ float dot4(const float4 a, const float4 b) {
    return fmaf(a.x, b.x, fmaf(a.y, b.y, fmaf(a.z, b.z, a.w * b.w)));
}

__device__ __forceinline__ float wave_sum(float v) {
#pragma unroll
    for (int off = 32; off > 0; off >>= 1) v += __shfl_xor(v, off);
    return v;
}

__device__ __forceinline__ void sm_merge(float& m, float& ss, int& a,
                                         float om, float os, int oa) {
    if (om > m || (om == m && oa < a)) {
        ss = os + ss * expf(m - om); m = om; a = oa;
    } else {
        ss += os * expf(om - m);
    }
}

__device__ __forceinline__ float bl(unsigned u) { return __uint_as_float(u << 16); }
__device__ __forceinline__ float bh(unsigned u) { return __uint_as_float(u & 0xffff0000u); }

__device__ __forceinline__ unsigned f2bf(float f) {   // RNE fp32->bf16
    unsigned u = __float_as_uint(f);
    return (u + 0x7fffu + ((u >> 16) & 1u)) >> 16;
}

// ---------------- init: h0 = enc ----------------
__global__ void init_kernel(const float* __restrict__ enc, float* __restrict__ h0) {
    for (int i = threadIdx.x; i < H; i += 256) h0[i] = enc[i];
}

// ---------------- one-time: lin_W fp32 -> packed bf16 ----------------
__global__ __launch_bounds__(512) void conv_kernel(const float* __restrict__ src,
                                                   unsigned short* __restrict__ dst) {
    const size_t idx = (size_t)blockIdx.x * 512 + threadIdx.x;  // 4,096,000 total
    const float4* s4 = (const float4*)src;
    float4 a = s4[2 * idx], b = s4[2 * idx + 1];
    uint4 o;
    o.x = f2bf(a.x) | (f2bf(a.y) << 16);
    o.y = f2bf(a.z) | (f2bf(a.w) << 16);
    o.z = f2bf(b.x) | (f2bf(b.y) << 16);
    o.w = f2bf(b.z) | (f2bf(b.w) << 16);
    ((uint4*)dst)[idx] = o;
}

// ---------------- per-step GRU (argmax feedback; logz[s-1] out) ----------------
__global__ __launch_bounds__(256) void gru_kernel(
    const float* __restrict__ emb, const float* __restrict__ W_ih,
    const float* __restrict__ W_hh, const float* __restrict__ b_ih,
    const float* __restrict__ b_hh, const float* __restrict__ h_cur,
    float* __restrict__ h_next, float* __restrict__ logz,
    const float* __restrict__ pm, const float* __restrict__ ps,
    const int* __restrict__ pa, int s) {
    const int tid = threadIdx.x;
    const int lane = tid & 63;
    const int wv = tid >> 6;
    const int b = blockIdx.x;
    const int i = b * 4 + wv;   // GRU output row (4 waves, one row each)

    // issue weight + h loads first; their latency overlaps the argmax reduce
    const float4* hp = (const float4*)h_cur;
    float4 hv[4];
    float4 WX0[4], WX1[4], WX2[4], WH0[4], WH1[4], WH2[4];
#pragma unroll
    for (int j = 0; j < 4; ++j) {
        const int idx = lane + 64 * j;
        hv[j] = hp[idx];
        WX0[j] = ((const float4*)(W_ih + (size_t)i * H))[idx];
        WX1[j] = ((const float4*)(W_ih + ((size_t)i + H) * H))[idx];
        WX2[j] = ((const float4*)(W_ih + ((size_t)i + 2 * H) * H))[idx];
        WH0[j] = ((const float4*)(W_hh + (size_t)i * H))[idx];
        WH1[j] = ((const float4*)(W_hh + ((size_t)i + H) * H))[idx];
        WH2[j] = ((const float4*)(W_hh + ((size_t)i + 2 * H) * H))[idx];
    }

    int tok = 0;
    if (s > 0) {
        float m = -3.4e38f, ss = 0.f;
        int a = 0x7fffffff;
#pragma unroll
        for (int k = 0; k < NB2 / 64; ++k)
            sm_merge(m, ss, a, pm[k * 64 + lane], ps[k * 64 + lane], pa[k * 64 + lane]);
#pragma unroll
        for (int off = 32; off > 0; off >>= 1) {
            float om = __shfl_xor(m, off), os = __shfl_xor(ss, off);
            int oa = __shfl_xor(a, off);
            sm_merge(m, ss, a, om, os, oa);
        }
        tok = a;
        if (b == 0 && tid == 0) logz[s - 1] = m + logf(ss);
    }

    const float4* xp = (const float4*)(emb + (size_t)tok * H);
    float4 xv[4];
#pragma unroll
    for (int j = 0; j < 4; ++j) xv[j] = xp[lane + 64 * j];

    float sx0 = 0, sx1 = 0, sx2 = 0, sh0 = 0, sh1 = 0, sh2 = 0;
#pragma unroll
    for (int j = 0; j < 4; ++j) {
        sx0 += dot4(WX0[j], xv[j]); sx1 += dot4(WX1[j], xv[j]); sx2 += dot4(WX2[j], xv[j]);
        sh0 += dot4(WH0[j], hv[j]); sh1 += dot4(WH1[j], hv[j]); sh2 += dot4(WH2[j], hv[j]);
    }
    sx0 = wave_sum(sx0); sx1 = wave_sum(sx1); sx2 = wave_sum(sx2);
    sh0 = wave_sum(sh0); sh1 = wave_sum(sh1); sh2 = wave_sum(sh2);
    if (lane == 0) {
        const float rg = 1.f / (1.f + expf(-((sx0 + b_ih[i]) + (sh0 + b_hh[i]))));
        const float zg = 1.f / (1.f + expf(-((sx1 + b_ih[i + H]) + (sh1 + b_hh[i + H]))));
        const float ng = tanhf((sx2 + b_ih[i + 2 * H]) + rg * (sh2 + b_hh[i + 2 * H]));
        h_next[i] = (1.f - zg) * ng + zg * h_cur[i];
    }
}

// ---------------- per-step logits: bf16 GEMV + fp32 rescue of near-max rows ----
__global__ __launch_bounds__(512, 4) void logits_bf16_kernel(
    const unsigned short* __restrict__ wbf, const float* __restrict__ lin_W,
    const float* __restrict__ lin_b, const float* __restrict__ h_src,
    float* __restrict__ orow, float* __restrict__ pm, float* __restrict__ ps,
    int* __restrict__ pa) {
    const int tid = threadIdx.x;
    const int lane = tid & 63;
    const int wv = tid >> 6;
    const int b = blockIdx.x;
    const int row0 = (b < 256) ? 63 * b : 16128 + 62 * (b - 256);
    const int nrows = (b < 256) ? 63 : 62;

    __shared__ float red_m[8], red_s[8];
    __shared__ float s_cm[8];
    __shared__ int s_ca[8];

    // h fragments in bf16-row layout: lane covers elems [8l..8l+7] and [512+8l..+7]
    const float4* h4 = (const float4*)h_src;
    const float4 ha0 = h4[2 * lane], ha1 = h4[2 * lane + 1];
    const float4 hb0 = h4[128 + 2 * lane], hb1 = h4[129 + 2 * lane];
    const float h0[8] = {ha0.x, ha0.y, ha0.z, ha0.w, ha1.x, ha1.y, ha1.z, ha1.w};
    const float h1[8] = {hb0.x, hb0.y, hb0.z, hb0.w, hb1.x, hb1.y, hb1.z, hb1.w};

    float lg[8];               // per-slot logit (wave-uniform after wave_sum)
    float m = -3.4e38f, ssum = 0.f;

#pragma unroll
    for (int half = 0; half < 2; ++half) {
        const int k0 = half * 4;
        uint4 qa[4], qb[4];
        int rr[4];
        bool val[4];
#pragma unroll
        for (int i2 = 0; i2 < 4; ++i2) {
            rr[i2] = wv + 8 * (k0 + i2);
            val[i2] = rr[i2] < nrows;
            const uint4* wp = (const uint4*)(wbf + (size_t)(row0 + (val[i2] ? rr[i2] : 0)) * H);
            qa[i2] = wp[lane];
            qb[i2] = wp[64 + lane];
        }
        __builtin_amdgcn_sched_barrier(0);
#pragma unroll
        for (int i2 = 0; i2 < 4; ++i2) {
            float a = 0.f;
            a = fmaf(bl(qa[i2].x), h0[0], a); a = fmaf(bh(qa[i2].x), h0[1], a);
            a = fmaf(bl(qa[i2].y), h0[2], a); a = fmaf(bh(qa[i2].y), h0[3], a);
            a = fmaf(bl(qa[i2].z), h0[4], a); a = fmaf(bh(qa[i2].z), h0[5], a);
            a = fmaf(bl(qa[i2].w), h0[6], a); a = fmaf(bh(qa[i2].w), h0[7], a);
            a = fmaf(bl(qb[i2].x), h1[0], a); a = fmaf(bh(qb[i2].x), h1[1], a);
            a = fmaf(bl(qb[i2].y), h1[2], a); a = fmaf(bh(qb[i2].y), h1[3], a);
            a = fmaf(bl(qb[i2].z), h1[4], a); a = fmaf(bh(qb[i2].z), h1[5], a);
            a = fmaf(bl(qb[i2].w), h1[6], a); a = fmaf(bh(qb[i2].w), h1[7], a);
            a = wave_sum(a);
            if (val[i2]) {
                const int col = row0 + rr[i2];
                a += lin_b[col];
                lg[k0 + i2] = a;
                if (lane == 0) __builtin_nontemporal_store(a, &orow[col]);
                if (a > m) { ssum *= expf(m - a); m = a; }
                ssum += expf(a - m);
            } else {
                lg[k0 + i2] = -3.4e38f;
            }
        }
    }
    if (lane == 0) { red_m[wv] = m; red_s[wv] = ssum; }
    __syncthreads();

    // block bf16 max (every thread computes from shared)
    float Mb = red_m[0];
#pragma unroll
    for (int w = 1; w < 8; ++w) Mb = fmaxf(Mb, red_m[w]);

    // fp32 rescue of candidate rows (wave-uniform predicate; ~0-4 per block)
    float cm = -3.4e38f;
    int ca = 0x7fffffff;
    float4 hv[4];
    bool loaded = false;
#pragma unroll
    for (int k = 0; k < 8; ++k) {
        if (lg[k] > Mb - DELTA) {
            const int row = row0 + wv + 8 * k;
            if (!loaded) {
#pragma unroll
                for (int j = 0; j < 4; ++j) hv[j] = h4[lane + 64 * j];
                loaded = true;
            }
            const float4* rp = (const float4*)(lin_W + (size_t)row * H);
            float a = 0.f;
#pragma unroll
            for (int j = 0; j < 4; ++j) a += dot4(rp[lane + 64 * j], hv[j]);
            a = wave_sum(a) + lin_b[row];
            if (a > cm || (a == cm && row < ca)) { cm = a; ca = row; }
        }
    }
    if (lane == 0) { s_cm[wv] = cm; s_ca[wv] = ca; }
    __syncthreads();
    if (tid == 0) {
        float M = red_m[0], S = red_s[0];
#pragma unroll
        for (int w = 1; w < 8; ++w) {   // merge sums (no argmax component)
            const float mw = red_m[w], sw = red_s[w];
            if (mw > M) { S = sw + S * expf(M - mw); M = mw; }
            else S += sw * expf(mw - M);
        }
        float CM = s_cm[0];
        int CA = s_ca[0];
#pragma unroll
        for (int w = 1; w < 8; ++w)
            if (s_cm[w] > CM || (s_cm[w] == CM && s_ca[w] < CA)) { CM = s_cm[w]; CA = s_ca[w]; }
        pm[b] = CM;                    // fp32-exact block max (argmax-safe)
        ps[b] = S * expf(M - CM);      // bf16 sumexp re-anchored to CM
        pa[b] = CA;
    }
}

// ---------------- fallback fp32 logits (if ws too small for bf16 copy) --------
__global__ __launch_bounds__(512, 4) void logits_fp32_kernel(
    const float* __restrict__ lin_W, const float* __restrict__ lin_b,
    const float* __restrict__ h_src, float* __restrict__ orow,
    float* __restrict__ pm, float* __restrict__ ps, int* __restrict__ pa) {
    const int tid = threadIdx.x;
    const int lane = tid & 63;
    const int wv = tid >> 6;
    const int b = blockIdx.x;
    const int row0 = (b < 256) ? 63 * b : 16128 + 62 * (b - 256);
    const int nrows = (b < 256) ? 63 : 62;

    __shared__ float red_m[8], red_s[8];
    __shared__ int red_a[8];

    const float4* h4 = (const float4*)h_src;
    float4 hr[4];
#pragma unroll
    for (int j = 0; j < 4; ++j) hr[j] = h4[lane + 64 * j];

    float m = -3.4e38f, ssum = 0.f;
    int arg = 0x7fffffff;
    for (int r = wv; r < nrows; r += 32) {
        const int rB = r + 8, rC = r + 16, rD = r + 24;
        const bool vB = rB < nrows, vC = rC < nrows, vD = rD < nrows;
        float4 wA[4], wB[4], wC[4], wD[4];
#pragma unroll
        for (int j = 0; j < 4; ++j) {
            const int idx = lane + 64 * j;
            wA[j] = ((const float4*)(lin_W + (size_t)(row0 + r) * H))[idx];
            wB[j] = ((const float4*)(lin_W + (size_t)(row0 + (vB ? rB : r)) * H))[idx];
            wC[j] = ((const float4*)(lin_W + (size_t)(row0 + (vC ? rC : r)) * H))[idx];
            wD[j] = ((const float4*)(lin_W + (size_t)(row0 + (vD ? rD : r)) * H))[idx];
        }
        __builtin_amdgcn_sched_barrier(0);
        float aA = 0, aB = 0, aC = 0, aD = 0;
#pragma unroll
        for (int j = 0; j < 4; ++j) {
            aA += dot4(wA[j], hr[j]); aB += dot4(wB[j], hr[j]);
            aC += dot4(wC[j], hr[j]); aD += dot4(wD[j], hr[j]);
        }
        aA = wave_sum(aA); aB = wave_sum(aB);
        aC = wave_sum(aC); aD = wave_sum(aD);
        aA += lin_b[row0 + r];
        if (lane == 0) __builtin_nontemporal_store(aA, &orow[row0 + r]);
        if (aA > m) { ssum *= expf(m - aA); m = aA; arg = row0 + r; }
        ssum += expf(aA - m);
        if (vB) {
            aB += lin_b[row0 + rB];
            if (lane == 0) __builtin_nontemporal_store(aB, &orow[row0 + rB]);
            if (aB > m) { ssum *= expf(m - aB); m = aB; arg = row0 + rB; }
            ssum += expf(aB - m);
        }
        if (vC) {
            aC += lin_b[row0 + rC];
            if (lane == 0) __builtin_nontemporal_store(aC, &orow[row0 + rC]);
            if (aC > m) { ssum *= expf(m - aC); m = aC; arg = row0 + rC; }
            ssum += expf(aC - m);
        }
        if (vD) {
            aD += lin_b[row0 + rD];
            if (lane == 0) __builtin_nontemporal_store(aD, &orow[row0 + rD]);
            if (aD > m) { ssum *= expf(m - aD); m = aD; arg = row0 + rD; }
            ssum += expf(aD - m);
        }
    }
    if (lane == 0) { red_m[wv] = m; red_s[wv] = ssum; red_a[wv] = arg; }
    __syncthreads();
    if (tid == 0) {
        float M = red_m[0], S = red_s[0];
        int A = red_a[0];
#pragma unroll
        for (int w = 1; w < 8; ++w) sm_merge(M, S, A, red_m[w], red_s[w], red_a[w]);
        pm[b] = M; ps[b] = S; pa[b] = A;
    }
}

// ---------------- final: out[s] -= logz[s] for s in 0..STEPS-2 ----------------
__global__ __launch_bounds__(256) void final_kernel(float* __restrict__ out,
                                                    const float* __restrict__ logz) {
    const int row = blockIdx.x >> 3;
    const int seg = blockIdx.x & 7;
    const float lz = logz[row];
    float4* p = (float4*)(out + (size_t)row * V) + seg * 1000;
    for (int i = threadIdx.x; i < 1000; i += 256) {
        float4 v = p[i];
        v.x -= lz; v.y -= lz; v.z -= lz; v.w -= lz;
        p[i] = v;
    }
}

// ---------------- tail: finalize out[STEPS-1] + write h_final ----------------
__global__ __launch_bounds__(256) void tail_kernel(
    float* __restrict__ out_last, const float* __restrict__ pm,
    const float* __restrict__ ps, const int* __restrict__ pa,
    const float* __restrict__ h_final, float* __restrict__ out_h) {
    const int tid = threadIdx.x;
    const int lane = tid & 63;
    const int b = blockIdx.x;
    float m = -3.4e38f, ss = 0.f;
    int a = 0x7fffffff;
#pragma unroll
    for (int k = 0; k < NB2 / 64; ++k)
        sm_merge(m, ss, a, pm[k * 64 + lane], ps[k * 64 + lane], pa[k * 64 + lane]);
#pragma unroll
    for (int off = 32; off > 0; off >>= 1) {
        float om = __shfl_xor(m, off), os = __shfl_xor(ss, off);
        int oa = __shfl_xor(a, off);
        sm_merge(m, ss, a, om, os, oa);
    }
    const float logZ = m + logf(ss);
    if (tid < 125) out_last[b * 125 + tid] -= logZ;
    if (b == 0)
        for (int i = tid; i < H; i += 256) out_h[i] = h_final[i];
}

extern "C" void kernel_launch(void* const* d_in, const int* in_sizes, int n_in,
                              void* d_out, int out_size, void* d_ws, size_t ws_size,
                              hipStream_t stream) {
    const float* enc = (const float*)d_in[0];
    const float* emb = (const float*)d_in[1];
    const float* W_ih = (const float*)d_in[2];
    const float* W_hh = (const float*)d_in[3];
    const float* b_ih = (const float*)d_in[4];
    const float* b_hh = (const float*)d_in[5];
    const float* lin_W = (const float*)d_in[6];
    const float* lin_b = (const float*)d_in[7];
    float* out = (float*)d_out;
    float* ws = (float*)d_ws;

    // ws: h_buf[2][H] | pm[NB2] | ps[NB2] | pa[NB2](int) | logz[STEPS] | pad | wbf
    float* h_buf = ws;
    float* pm = ws + 2 * H;
    float* ps = pm + NB2;
    int* pa = (int*)(ps + NB2);
    float* logz = (float*)(pa + NB2);
    unsigned short* wbf = (unsigned short*)((char*)d_ws + 16384);
    const size_t need = 16384 + (size_t)V * H * 2;
    const bool bf16path = ws_size >= need;

    init_kernel<<<1, 256, 0, stream>>>(enc, h_buf);
    if (bf16path)
        conv_kernel<<<V * H / 8 / 512, 512, 0, stream>>>(lin_W, wbf);
    for (int s = 0; s < STEPS; ++s) {
        float* h_cur = h_buf + (s & 1) * H;
        float* h_next = h_buf + ((s + 1) & 1) * H;
        gru_kernel<<<NB1, 256, 0, stream>>>(emb, W_ih, W_hh, b_ih, b_hh,
                                            h_cur, h_next, logz, pm, ps, pa, s);
        if (bf16path)
            logits_bf16_kernel<<<NB2, 512, 0, stream>>>(wbf, lin_W, lin_b, h_next,
                                                        out + (size_t)s * V, pm, ps, pa);
        else
            logits_fp32_kernel<<<NB2, 512, 0, stream>>>(lin_W, lin_b, h_next,
                                                        out + (size_t)s * V, pm, ps, pa);
    }
    final_kernel<<<(STEPS - 1) * 8, 256, 0, stream>>>(out, logz);
    tail_kernel<<<NB1, 256, 0, stream>>>(out + (size_t)(STEPS - 1) * V, pm, ps, pa,
                                         h_buf + (STEPS & 1) * H,
                                         out + (size_t)V * STEPS);
}